// Round 6
// baseline (189.934 us; speedup 1.0000x reference)
//
#include <hip/hip_runtime.h>
#include <hip/hip_bf16.h>

// b=1, c=256, h=w=64 -> n=4096 pixels, 4 heads, hd=64, 32 groups x 8 ch.
// scale = hd^-0.5 = 0.125, folded into Wq (K0) and bq (K1 epilogue).
#define NPIX 4096
#define CCH  256
#define HD   64
#define GSIZE 32768   // 8 ch * 4096 pix per group (contiguous)

typedef __bf16 bf16x8 __attribute__((ext_vector_type(8)));
typedef __bf16 bf16x4 __attribute__((ext_vector_type(4)));
typedef float  f32x4  __attribute__((ext_vector_type(4)));

#define PPITCH 72    // attn P-tile pitch (bf16): 144B rows, 16B-aligned
#define CPITCH 68    // attn combine pitch (f32)
#define XPITCH 264   // X/F panel pitch (bf16): 528B rows, 16B-aligned, ~2-way frag reads

// MFMA 16x16x32_bf16 layouts (verified m89/m91; used R2-R5):
//   A[m=lane&15][k=quad*8+j]  (8 contig k from layout [m][k])
//   B[k=quad*8+j][n=lane&15]  (8 contig k from layout [n][k])
//   C/D: row m = quad*4+reg, col n = lane&15

// ---------------------------------------------------------------------------
// K0: blocks 0..31: per-group stats -> per-CHANNEL affine coeffs ach/bch.
//     blocks 32..95: weight fp32->bf16 convert (Wq scaled 0.125).
// ---------------------------------------------------------------------------
__global__ __launch_bounds__(1024) void stats_wconv(
    const float* __restrict__ X, const float* __restrict__ gamma,
    const float* __restrict__ beta,
    const float* __restrict__ Wq, const float* __restrict__ Wk,
    const float* __restrict__ Wv, const float* __restrict__ Wp,
    float* __restrict__ ach, float* __restrict__ bch, __bf16* __restrict__ Wb)
{
    __shared__ float red[2][16];
    __shared__ float st[2];
    const int bid = blockIdx.x, t = threadIdx.x;

    if (bid < 32) {
        const int g = bid;
        const float* Xg = X + g * GSIZE;
        float sum = 0.f, ssq = 0.f;
        for (int i = t * 4; i < GSIZE; i += 4096) {
            float4 v = *(const float4*)(Xg + i);
            sum += v.x + v.y + v.z + v.w;
            ssq += v.x * v.x + v.y * v.y + v.z * v.z + v.w * v.w;
        }
        #pragma unroll
        for (int off = 1; off < 64; off <<= 1) {
            sum += __shfl_xor(sum, off);
            ssq += __shfl_xor(ssq, off);
        }
        const int wv = t >> 6;
        if ((t & 63) == 0) { red[0][wv] = sum; red[1][wv] = ssq; }
        __syncthreads();
        if (t == 0) {
            float s = 0.f, q = 0.f;
            #pragma unroll
            for (int w = 0; w < 16; ++w) { s += red[0][w]; q += red[1][w]; }
            const float mu  = s * (1.f / GSIZE);
            const float var = q * (1.f / GSIZE) - mu * mu;
            st[0] = mu;
            st[1] = rsqrtf(var + 1e-6f);
        }
        __syncthreads();
        if (t < 8) {
            const int c = g * 8 + t;
            const float a = gamma[c] * st[1];
            ach[c] = a;
            bch[c] = beta[c] - st[0] * a;
        }
    } else {
        const int j = (bid - 32) * 4096 + t * 4;    // 0..262143
        const int m = j >> 16;
        const float* W = (m == 0) ? Wq : (m == 1) ? Wk : (m == 2) ? Wv : Wp;
        const float sc = (m == 0) ? 0.125f : 1.f;
        float4 v = *(const float4*)(W + (j & 65535));
        bf16x4 o;
        o[0] = (__bf16)(v.x * sc); o[1] = (__bf16)(v.y * sc);
        o[2] = (__bf16)(v.z * sc); o[3] = (__bf16)(v.w * sc);
        *(bf16x4*)(Wb + j) = o;
    }
}

// ---------------------------------------------------------------------------
// K1: fused GroupNorm-apply + QKV MFMA GEMM. grid (64 pixblk, 3 z), 256 thr.
// Stage affine-applied bf16 X panel [64 pix][256 c] in LDS once; each wave
// computes 16 pix x 256 outc for its z.
//   z<2 (Q/K): A=W (m=oc), B=X (n=pix) -> [head][pix][d] bf16x4 stores.
//   z=2 (V):   A=X (m=pix), B=W (n=oc) -> [c][pix]       bf16x4 stores.
// ---------------------------------------------------------------------------
__global__ __launch_bounds__(256) void gn_qkv(
    const float* __restrict__ X, const float* __restrict__ ach,
    const float* __restrict__ bch, const __bf16* __restrict__ Wb,
    const float* __restrict__ bq, const float* __restrict__ bk,
    const float* __restrict__ bv,
    __bf16* __restrict__ Qb, __bf16* __restrict__ Kb, __bf16* __restrict__ Vb)
{
    __shared__ __bf16 tile[64 * XPITCH];   // [pix][c]

    const int t = threadIdx.x, lane = t & 63, wave = t >> 6;
    const int l16 = lane & 15, quad = lane >> 4;
    const int p0 = blockIdx.x * 64, z = blockIdx.y;

    // stage: wave w handles channels [w*64, w*64+64), lane = pix
    #pragma unroll 4
    for (int i = 0; i < 16; ++i) {
        const int c4 = wave * 64 + i * 4;
        float4 a4 = *(const float4*)(ach + c4);
        float4 b4 = *(const float4*)(bch + c4);
        bf16x4 pk;
        pk[0] = (__bf16)(X[(c4 + 0) * NPIX + p0 + lane] * a4.x + b4.x);
        pk[1] = (__bf16)(X[(c4 + 1) * NPIX + p0 + lane] * a4.y + b4.y);
        pk[2] = (__bf16)(X[(c4 + 2) * NPIX + p0 + lane] * a4.z + b4.z);
        pk[3] = (__bf16)(X[(c4 + 3) * NPIX + p0 + lane] * a4.w + b4.w);
        *(bf16x4*)(tile + lane * XPITCH + c4) = pk;
    }
    __syncthreads();

    const int pw = wave * 16;
    bf16x8 xf[8];
    #pragma unroll
    for (int kc = 0; kc < 8; ++kc)
        xf[kc] = *(const bf16x8*)(tile + (pw + l16) * XPITCH + kc * 32 + quad * 8);

    const __bf16* Wz = Wb + z * 65536;
    const float* bias = (z == 0) ? bq : (z == 1) ? bk : bv;

    if (z < 2) {
        const float qs = (z == 0) ? 0.125f : 1.f;
        __bf16* dst = (z == 0) ? Qb : Kb;
        #pragma unroll
        for (int grp = 0; grp < 4; ++grp) {
            f32x4 acc[4] = {};
            #pragma unroll
            for (int kc = 0; kc < 8; ++kc) {
                #pragma unroll
                for (int u = 0; u < 4; ++u) {
                    bf16x8 wf = *(const bf16x8*)(Wz + ((grp * 4 + u) * 16 + l16) * CCH + kc * 32 + quad * 8);
                    acc[u] = __builtin_amdgcn_mfma_f32_16x16x32_bf16(wf, xf[kc], acc[u], 0, 0, 0);
                }
            }
            #pragma unroll
            for (int u = 0; u < 4; ++u) {
                const int ot = grp * 4 + u;
                float4 bz = *(const float4*)(bias + ot * 16 + quad * 4);
                bf16x4 o;
                o[0] = (__bf16)(acc[u][0] + bz.x * qs);
                o[1] = (__bf16)(acc[u][1] + bz.y * qs);
                o[2] = (__bf16)(acc[u][2] + bz.z * qs);
                o[3] = (__bf16)(acc[u][3] + bz.w * qs);
                const int head = ot >> 2, dloc = (ot & 3) * 16 + quad * 4;
                *(bf16x4*)(dst + head * (NPIX * HD) + (p0 + pw + l16) * HD + dloc) = o;
            }
        }
    } else {
        #pragma unroll
        for (int grp = 0; grp < 4; ++grp) {
            f32x4 acc[4] = {};
            #pragma unroll
            for (int kc = 0; kc < 8; ++kc) {
                #pragma unroll
                for (int u = 0; u < 4; ++u) {
                    bf16x8 wf = *(const bf16x8*)(Wz + ((grp * 4 + u) * 16 + l16) * CCH + kc * 32 + quad * 8);
                    acc[u] = __builtin_amdgcn_mfma_f32_16x16x32_bf16(xf[kc], wf, acc[u], 0, 0, 0);
                }
            }
            #pragma unroll
            for (int u = 0; u < 4; ++u) {
                const int oc = (grp * 4 + u) * 16 + l16;
                const float bz = bias[oc];
                bf16x4 o;
                o[0] = (__bf16)(acc[u][0] + bz); o[1] = (__bf16)(acc[u][1] + bz);
                o[2] = (__bf16)(acc[u][2] + bz); o[3] = (__bf16)(acc[u][3] + bz);
                *(bf16x4*)(Vb + oc * NPIX + p0 + pw + quad * 4) = o;
            }
        }
    }
}

// ---------------------------------------------------------------------------
// K2: bf16 MFMA attention, max-free softmax (scores bounded), S^T orientation,
// software-pipelined: K double-buffered in regs (prefetch it+1), V issued at
// iter top and consumed after S/exp/LDS. No barriers in main loop.
// Block = 1 head x 32 q-rows, 4 waves; wave w owns keys [w*1024,(w+1)*1024).
// Output bf16 flat F[pix*256 + head*64 + d].
// ---------------------------------------------------------------------------
__global__ __launch_bounds__(256, 2) void attn_mfma(
    const __bf16* __restrict__ Qb, const __bf16* __restrict__ Kb,
    const __bf16* __restrict__ Vb, __bf16* __restrict__ Sb)
{
    __shared__ __bf16 pt[4][32 * PPITCH];     // per-wave P [qrow32][key64]
    __shared__ float  co[4][32 * CPITCH];     // per-wave O^T partial [qrow][d]
    __shared__ float  cl[4][32];              // per-wave l partial

    const int t = threadIdx.x, lane = t & 63, wave = t >> 6;
    const int l16 = lane & 15, quad = lane >> 4;

    const int bid  = blockIdx.x;
    const int head = (bid & 7) >> 1;                   // XCD-pair pinning
    const int tile = ((bid >> 3) << 1) | (bid & 1);    // 0..127
    const int p0   = tile * 32;

    const __bf16* Qh = Qb + head * (NPIX * HD);
    const __bf16* Kh = Kb + head * (NPIX * HD);
    const __bf16* Vh = Vb + head * (HD * NPIX);

    // Q B-frags: B[k=d][n=qrow] from layout [qrow][d]
    bf16x8 bqf[2][2];
    #pragma unroll
    for (int rs = 0; rs < 2; ++rs) {
        const __bf16* qp = Qh + (p0 + rs * 16 + l16) * HD;
        bqf[rs][0] = *(const bf16x8*)(qp + quad * 8);
        bqf[rs][1] = *(const bf16x8*)(qp + 32 + quad * 8);
    }

    bf16x8 ones;
    #pragma unroll
    for (int j = 0; j < 8; ++j) ones[j] = (__bf16)1.0f;

    f32x4 l_acc[2] = {};
    f32x4 o_acc[4][2] = {};   // [dt][rs]

    __bf16* ptw = pt[wave];

    // prologue: load K for it=0
    bf16x8 kc0[4], kc1[4];
    #pragma unroll
    for (int nt = 0; nt < 4; ++nt) {
        const __bf16* kp = Kh + (wave * 1024 + nt * 16 + l16) * HD;
        kc0[nt] = *(const bf16x8*)(kp + quad * 8);
        kc1[nt] = *(const bf16x8*)(kp + 32 + quad * 8);
    }

    #pragma unroll 2
    for (int it = 0; it < 16; ++it) {
        const int kb = wave * 1024 + it * 64;

        // ---- V loads issued early (consumed after S/exp/LDS) ----
        bf16x8 v0[4], v1[4];
        #pragma unroll
        for (int dt = 0; dt < 4; ++dt) {
            const __bf16* vp = Vh + (dt * 16 + l16) * NPIX + kb;
            v0[dt] = *(const bf16x8*)(vp + quad * 8);
            v1[dt] = *(const bf16x8*)(vp + 32 + quad * 8);
        }
        // ---- K prefetch for it+1 (wraps to own start on last iter; unused) ----
        bf16x8 kn0[4], kn1[4];
        {
            const int kbn = wave * 1024 + ((it + 1) & 15) * 64;
            #pragma unroll
            for (int nt = 0; nt < 4; ++nt) {
                const __bf16* kp = Kh + (kbn + nt * 16 + l16) * HD;
                kn0[nt] = *(const bf16x8*)(kp + quad * 8);
                kn1[nt] = *(const bf16x8*)(kp + 32 + quad * 8);
            }
        }

        // ---- S^T = K Q^T : C (key=kt*16+quad*4+r, qrow=rs*16+l16) ----
        f32x4 st[4][2] = {};
        #pragma unroll
        for (int kt = 0; kt < 4; ++kt) {
            #pragma unroll
            for (int rs = 0; rs < 2; ++rs) {
                st[kt][rs] = __builtin_amdgcn_mfma_f32_16x16x32_bf16(kc0[kt], bqf[rs][0], st[kt][rs], 0, 0, 0);
                st[kt][rs] = __builtin_amdgcn_mfma_f32_16x16x32_bf16(kc1[kt], bqf[rs][1], st[kt][rs], 0, 0, 0);
            }
        }

        // ---- P = exp(S^T), packed b64 stores ----
        #pragma unroll
        for (int kt = 0; kt < 4; ++kt) {
            #pragma unroll
            for (int rs = 0; rs < 2; ++rs) {
                bf16x4 p;
                p[0] = (__bf16)__expf(st[kt][rs][0]);
                p[1] = (__bf16)__expf(st[kt][rs][1]);
                p[2] = (__bf16)__expf(st[kt][rs][2]);
                p[3] = (__bf16)__expf(st[kt][rs][3]);
                *(bf16x4*)(ptw + (rs * 16 + l16) * PPITCH + kt * 16 + quad * 4) = p;
            }
        }

        // ---- P B-frags (same-wave LDS RAW, waitcnt only) ----
        bf16x8 bp[2][2];
        #pragma unroll
        for (int rs = 0; rs < 2; ++rs) {
            bp[rs][0] = *(const bf16x8*)(ptw + (rs * 16 + l16) * PPITCH + quad * 8);
            bp[rs][1] = *(const bf16x8*)(ptw + (rs * 16 + l16) * PPITCH + 32 + quad * 8);
        }

        // ---- l += rowsum(P) on the matrix pipe ----
        #pragma unroll
        for (int rs = 0; rs < 2; ++rs) {
            l_acc[rs] = __builtin_amdgcn_mfma_f32_16x16x32_bf16(ones, bp[rs][0], l_acc[rs], 0, 0, 0);
            l_acc[rs] = __builtin_amdgcn_mfma_f32_16x16x32_bf16(ones, bp[rs][1], l_acc[rs], 0, 0, 0);
        }

        // ---- O^T += V^T P^T ----
        #pragma unroll
        for (int dt = 0; dt < 4; ++dt) {
            #pragma unroll
            for (int rs = 0; rs < 2; ++rs) {
                o_acc[dt][rs] = __builtin_amdgcn_mfma_f32_16x16x32_bf16(v0[dt], bp[rs][0], o_acc[dt][rs], 0, 0, 0);
                o_acc[dt][rs] = __builtin_amdgcn_mfma_f32_16x16x32_bf16(v1[dt], bp[rs][1], o_acc[dt][rs], 0, 0, 0);
            }
        }

        // ---- swap prefetched K into current ----
        #pragma unroll
        for (int nt = 0; nt < 4; ++nt) { kc0[nt] = kn0[nt]; kc1[nt] = kn1[nt]; }
    }

    // ---- wave partials (plain sums) -> LDS ----
    #pragma unroll
    for (int dt = 0; dt < 4; ++dt)
        #pragma unroll
        for (int rs = 0; rs < 2; ++rs)
            *(f32x4*)(&co[wave][(rs * 16 + l16) * CPITCH + dt * 16 + quad * 4]) = o_acc[dt][rs];
    if (quad == 0) {
        cl[wave][l16]      = l_acc[0][0];
        cl[wave][16 + l16] = l_acc[1][0];
    }
    __syncthreads();

    // ---- merge = sum over 4 waves, divide, store bf16 F-layout ----
    {
        const int row = t >> 3, dg = (t & 7) * 8;
        const float l = cl[0][row] + cl[1][row] + cl[2][row] + cl[3][row];
        const float inv = 1.f / l;
        f32x4 s0 = {}, s1 = {};
        #pragma unroll
        for (int w = 0; w < 4; ++w) {
            s0 += *(const f32x4*)(&co[w][row * CPITCH + dg]);
            s1 += *(const f32x4*)(&co[w][row * CPITCH + dg + 4]);
        }
        bf16x8 o;
        o[0] = (__bf16)(s0[0] * inv); o[1] = (__bf16)(s0[1] * inv);
        o[2] = (__bf16)(s0[2] * inv); o[3] = (__bf16)(s0[3] * inv);
        o[4] = (__bf16)(s1[0] * inv); o[5] = (__bf16)(s1[1] * inv);
        o[6] = (__bf16)(s1[2] * inv); o[7] = (__bf16)(s1[3] * inv);
        *(bf16x8*)(Sb + (p0 + row) * CCH + head * HD + dg) = o;
    }
}

// ---------------------------------------------------------------------------
// K3: proj bf16 MFMA GEMM + bias + residual, fp32 out [c][pix].
// Torch scramble: In[c~][p] = F_flat[c~*4096 + p] (strided k) -> stage panel
// In[0:256][p0:p0+64] into LDS as Bs[p][c~] once per block. grid (64, 2):
// each block computes 128 outc (2 panel stagings per pixblk instead of 8).
// A = Bs rows (m=pix), B = Wp (n=oc); C (pix=quad*4+r, oc=l16) -> f32x4.
// ---------------------------------------------------------------------------
__global__ __launch_bounds__(256) void gemm_proj(
    const __bf16* __restrict__ Sb, const __bf16* __restrict__ Wpb,
    const float* __restrict__ bias, const float* __restrict__ X,
    float* __restrict__ Out)
{
    __shared__ __bf16 Bs[64 * XPITCH];   // [p local][c~]

    const int t = threadIdx.x, lane = t & 63, wave = t >> 6;
    const int l16 = lane & 15, quad = lane >> 4;
    const int p0  = blockIdx.x * 64;
    const int ocg = blockIdx.y * 128;

    // stage In[c~][p0..p0+63] -> Bs[p][c~]; thread t owns channel c~ = t
    #pragma unroll
    for (int pg = 0; pg < 8; ++pg) {
        bf16x8 v = *(const bf16x8*)(Sb + t * NPIX + p0 + pg * 8);
        #pragma unroll
        for (int j = 0; j < 8; ++j)
            Bs[(pg * 8 + j) * XPITCH + t] = v[j];
    }
    __syncthreads();

    const int pw = wave * 16;
    bf16x8 af[8];
    #pragma unroll
    for (int kc = 0; kc < 8; ++kc)
        af[kc] = *(const bf16x8*)(Bs + (pw + l16) * XPITCH + kc * 32 + quad * 8);

    #pragma unroll
    for (int grp = 0; grp < 2; ++grp) {
        f32x4 acc[4] = {};
        #pragma unroll
        for (int kc = 0; kc < 8; ++kc) {
            #pragma unroll
            for (int u = 0; u < 4; ++u) {
                bf16x8 wf = *(const bf16x8*)(Wpb + (ocg + (grp * 4 + u) * 16 + l16) * CCH + kc * 32 + quad * 8);
                acc[u] = __builtin_amdgcn_mfma_f32_16x16x32_bf16(af[kc], wf, acc[u], 0, 0, 0);
            }
        }
        #pragma unroll
        for (int u = 0; u < 4; ++u) {
            const int oc  = ocg + (grp * 4 + u) * 16 + l16;
            const int pix = p0 + pw + quad * 4;
            const float bz = bias[oc];
            f32x4 r4 = *(const f32x4*)(X + oc * NPIX + pix);
            f32x4 y;
            y[0] = acc[u][0] + bz + r4[0];
            y[1] = acc[u][1] + bz + r4[1];
            y[2] = acc[u][2] + bz + r4[2];
            y[3] = acc[u][3] + bz + r4[3];
            *(f32x4*)(Out + oc * NPIX + pix) = y;
        }
    }
}

// ---------------------------------------------------------------------------
extern "C" void kernel_launch(void* const* d_in, const int* in_sizes, int n_in,
                              void* d_out, int out_size, void* d_ws, size_t ws_size,
                              hipStream_t stream)
{
    const float* x     = (const float*)d_in[0];
    const float* gamma = (const float*)d_in[1];
    const float* beta  = (const float*)d_in[2];
    const float* Wq    = (const float*)d_in[3];
    const float* bq    = (const float*)d_in[4];
    const float* Wk    = (const float*)d_in[5];
    const float* bk    = (const float*)d_in[6];
    const float* Wv    = (const float*)d_in[7];
    const float* bv    = (const float*)d_in[8];
    const float* Wp    = (const float*)d_in[9];
    const float* bp    = (const float*)d_in[10];
    float* out = (float*)d_out;

    char* ws = (char*)d_ws;
    float*  ach = (float*)(ws);                // 1KB  per-channel affine a
    float*  bch = (float*)(ws + 4096);         // 1KB  per-channel affine b
    __bf16* Wb  = (__bf16*)(ws + 65536);       // 512KB bf16 4x[256][256]
    __bf16* Qb  = (__bf16*)(ws + (1 << 20));   // 2MB bf16 [head][pix][64]
    __bf16* Kb  = (__bf16*)(ws + (3 << 20));   // 2MB bf16 [head][pix][64]
    __bf16* Vb  = (__bf16*)(ws + (5 << 20));   // 2MB bf16 [c][pix]
    __bf16* Sb  = (__bf16*)(ws + (7 << 20));   // 2MB bf16 flat F

    stats_wconv<<<96, 1024, 0, stream>>>(x, gamma, beta, Wq, Wk, Wv, Wp,
                                         ach, bch, Wb);

    dim3 gq(64, 3);
    gn_qkv<<<gq, 256, 0, stream>>>(x, ach, bch, Wb, bq, bk, bv, Qb, Kb, Vb);

    attn_mfma<<<512, 256, 0, stream>>>(Qb, Kb, Vb, Sb);

    dim3 gp(64, 2);
    gemm_proj<<<gp, 256, 0, stream>>>(Sb, Wb + 3 * 65536, bp, x, out);
}